// Round 15
// baseline (115.269 us; speedup 1.0000x reference)
//
#include <hip/hip_runtime.h>

// CRF forward (log-partition), SEQ=512, BATCH=1024, TAGS=32, fp32 in/out.
//
// R24 = R23 resubmission (bench infra failed: "container failed twice";
// no kernel signal). Audit found no deadlock/fault path: barrier parity
// matched across all 4 waves; raw-ring WAR fenced by same-wave lgkmcnt(0);
// FF parity disjoint producer/consumer; garbage over-reads in-bounds.
//
// R23 design: gld_lds producer + light consumer (synthesis of R21 + R22).
// R22 post-mortem: VGPR 132->52 proved the producer's register staging was
// sunk by the allocator -> ~8 serialized ~400cy loads = the invariant
// ~3200 cy/chunk. Consumer strip itself was sound (~600 cy/chunk fast path).
// Producer uses the mechanism that cannot be sunk and needs no VGPRs -
// global_load_lds into a 4-deep RAW ring with counted vmcnt (27 steady;
// 18/9/0 tail), then in its slack transforms raw -> exp2'd F (ds_read_b128
// own lanes, 32 exp2, ds_write_b128 into the 2-deep FF parity buffer) +
// mask + all-ones flag. Consumer = R22 fast path.
// PRE-COMMIT (carried): if dispatch stays ~42us, the period is a floor
// neither wave's issue stream explains -> declare done next round.
// Algorithm (validated R13-R22): fwd alpha <- f_t o (E alpha) t=0..255;
// bwd u <- E^T (f_t o u) t=511..256; out = ln2*(c2f+c2b+log2(dot(u,alpha))).

constexpr int SEQ = 512, BATCH = 1024, TAGS = 32;
constexpr int BPB = 8;               // batches per block
constexpr int CH = 8;                // steps per chunk
constexpr int NCH = (SEQ / 2) / CH;  // 32 chunks per direction
constexpr int RRN = 4;               // raw ring depth (chunks)
constexpr int SSTRIDE = BPB * TAGS;  // step stride in LDS dwords (256)
constexpr int FSLOT = CH * SSTRIDE;  // dwords per chunk slot (2048)
constexpr int RSLOT = FSLOT + 64;    // raw slot: feats + 64 mask dwords
constexpr int MSLOT = CH * BPB;      // mask dwords per chunk (64)

#define LOG2E 1.4426950408889634f
#define LN2   0.6931471805599453f

typedef __attribute__((ext_vector_type(8))) short short8;
typedef __attribute__((ext_vector_type(4))) float float4v;
union Frag8 { unsigned u[4]; short8 v; };

__device__ __forceinline__ unsigned pk_rn(float x, float y) {  // bf16 pack, x->low
  return __builtin_amdgcn_perm(__float_as_uint(y) + 0x8000u,
                               __float_as_uint(x) + 0x8000u, 0x07060302u);
}
__device__ __forceinline__ unsigned pk_tr(float x, float y) {  // trunc pack, x->low
  return __builtin_amdgcn_perm(__float_as_uint(y), __float_as_uint(x), 0x07060302u);
}

__device__ __forceinline__ void gld16(const float* g, float* l) {
  __builtin_amdgcn_global_load_lds((const __attribute__((address_space(1))) void*)g,
                                   (__attribute__((address_space(3))) void*)l, 16, 0, 0);
}
__device__ __forceinline__ void gld4(const float* g, float* l) {
  __builtin_amdgcn_global_load_lds((const __attribute__((address_space(1))) void*)g,
                                   (__attribute__((address_space(3))) void*)l, 4, 0, 0);
}

// ---------- producer: gld_lds raw ring -> exp2 transform -> FF ----------
template <bool FWD>
__device__ __forceinline__ void produce(
    const float* __restrict__ feats, const float* __restrict__ maskp,
    float* __restrict__ RAWd, float* __restrict__ FFd, float* __restrict__ MMd,
    unsigned* __restrict__ FLGd, int b0, int lane) {
  // pre-swizzled global source (m173): lane l fetches tag-group
  // (l&7)^((l>>3)&7) of batch l>>3 so the linear gld16 dest realizes the
  // swizzled layout loc b*32 + (g^(b&7))*4.
  const int bs = lane >> 3;
  const int tg = 4 * ((lane & 7) ^ (bs & 7));
  const size_t t0off = FWD ? 0 : (size_t)(SEQ - 1) * BATCH * TAGS;
  const float* gF0 = feats + t0off + (size_t)(b0 + bs) * TAGS + tg;
  const float* gM0 = maskp +
      (FWD ? (size_t)(lane >> 3) : (size_t)(SEQ - 1 - (lane >> 3))) * BATCH +
      b0 + (lane & 7);
  const ptrdiff_t fstep = FWD ? (ptrdiff_t)(BATCH * TAGS) : -(ptrdiff_t)(BATCH * TAGS);
  const ptrdiff_t mstep = FWD ? (ptrdiff_t)BATCH : -(ptrdiff_t)BATCH;

  auto FILL = [&](int k) {  // 9 vmcnt events
    float* rb = RAWd + (k & (RRN - 1)) * RSLOT;
#pragma unroll
    for (int j = 0; j < CH; ++j)
      gld16(gF0 + (ptrdiff_t)(CH * k + j) * fstep, rb + j * SSTRIDE);
    gld4(gM0 + (ptrdiff_t)(CH * k) * mstep, rb + FSLOT);
  };

  auto XFORM = [&](int c) {  // raw chunk c -> exp'd FF[c&1] (+mask, +flag)
    const float* rb = RAWd + (c & (RRN - 1)) * RSLOT;
    float* fb = FFd + (c & 1) * FSLOT;
    const float mraw = rb[FSLOT + lane];
    const unsigned flag = (__ballot(mraw != 0.0f) == ~0ull) ? 1u : 0u;
#pragma unroll
    for (int j = 0; j < CH; ++j) {
      const float4v r = *(const float4v*)(rb + j * SSTRIDE + lane * 4);
      float4v e;
#pragma unroll
      for (int i = 0; i < 4; ++i) e[i] = __builtin_amdgcn_exp2f(r[i] * LOG2E);
      *(float4v*)(fb + j * SSTRIDE + lane * 4) = e;
    }
    MMd[(c & 1) * MSLOT + lane] = mraw;
    if (lane == 0) FLGd[c & 1] = flag;
  };

  FILL(0); FILL(1); FILL(2); FILL(3);                 // 36 in flight
  asm volatile("s_waitcnt vmcnt(27)" ::: "memory");   // raw chunk 0 landed
  XFORM(0);
  asm volatile("s_waitcnt lgkmcnt(0)" ::: "memory");
  __builtin_amdgcn_s_barrier();                       // B0: FF chunk 0 ready
  for (int k = 0; k < NCH; ++k) {
    if (k < NCH - 4) {
      FILL(k + 4);                                    // raw slot k&3 (safe: own
                                                      // XFORM(k) reads done)
      asm volatile("s_waitcnt vmcnt(27)" ::: "memory");  // raw k+1 landed
    } else if (k == NCH - 4) {
      asm volatile("s_waitcnt vmcnt(18)" ::: "memory");
    } else if (k == NCH - 3) {
      asm volatile("s_waitcnt vmcnt(9)" ::: "memory");
    } else if (k == NCH - 2) {
      asm volatile("s_waitcnt vmcnt(0)" ::: "memory");
    }
    if (k + 1 < NCH) XFORM(k + 1);
    asm volatile("s_waitcnt lgkmcnt(0)" ::: "memory");
    __builtin_amdgcn_s_barrier();                     // B(k+1): FF k+1 ready
  }
  __syncthreads();  // junction barrier (match consumers)
}

// ---------------- consumer: run one direction's chain ----------------
template <bool FWD>
__device__ __forceinline__ void consume(
    const float* __restrict__ trans, float* __restrict__ out,
    const float* __restrict__ FFd, const float* __restrict__ MMd,
    const unsigned* __restrict__ FLGd,
    float* __restrict__ vbuf, float* __restrict__ c2buf, int b0, int lane) {
  const int s = lane & 15, q = lane >> 4;
  // columns s>=8 carry garbage (don't-care; over-reads land in-bounds).

  // sigma-permuted E fragments (A-operand layout: row=l&15, k in sig order
  // {4q..4q+3, 16+4q..16+4q+3} - verified R9-R22).
  int sig[8];
#pragma unroll
  for (int i = 0; i < 8; ++i) sig[i] = (i < 4) ? (4 * q + i) : (16 + 4 * q + (i - 4));
  Frag8 e0, e1;  // FWD: E rows (D=E*B). BWD: E^T rows.
#pragma unroll
  for (int p = 0; p < 4; ++p) {
    if (FWD) {
      e0.u[p] = pk_rn(__builtin_amdgcn_exp2f(trans[s * TAGS + sig[2 * p]] * LOG2E),
                      __builtin_amdgcn_exp2f(trans[s * TAGS + sig[2 * p + 1]] * LOG2E));
      e1.u[p] = pk_rn(__builtin_amdgcn_exp2f(trans[(16 + s) * TAGS + sig[2 * p]] * LOG2E),
                      __builtin_amdgcn_exp2f(trans[(16 + s) * TAGS + sig[2 * p + 1]] * LOG2E));
    } else {
      e0.u[p] = pk_rn(__builtin_amdgcn_exp2f(trans[sig[2 * p] * TAGS + s] * LOG2E),
                      __builtin_amdgcn_exp2f(trans[sig[2 * p + 1] * TAGS + s] * LOG2E));
      e1.u[p] = pk_rn(__builtin_amdgcn_exp2f(trans[sig[2 * p] * TAGS + 16 + s] * LOG2E),
                      __builtin_amdgcn_exp2f(trans[sig[2 * p + 1] * TAGS + 16 + s] * LOG2E));
    }
  }

  // state: a[i] = vec[j][b=s], j = sig-mapped.
  float a[8];
#pragma unroll
  for (int i = 0; i < 8; ++i) {
    if (FWD) a[i] = (q == 3 && i == 6) ? 1.0f : 0.0f;  // alpha0 = e_30
    else a[i] = __builtin_amdgcn_exp2f(
        trans[31 * TAGS + ((i < 4) ? (4 * q + i) : (16 + 4 * q + (i - 4)))] * LOG2E);
  }
  Frag8 Bf;
  Bf.u[0] = pk_tr(a[0], a[1]); Bf.u[1] = pk_tr(a[2], a[3]);
  Bf.u[2] = pk_tr(a[4], a[5]); Bf.u[3] = pk_tr(a[6], a[7]);
  float c2 = 0.f;
  const float4v zerov = {0.f, 0.f, 0.f, 0.f};

  // LDS read offsets (dwords within a step slot); <=2-way bank aliasing.
  const int off0 = s * 32 + ((q ^ (s & 7)) << 2);
  const int off1 = s * 32 + (((q + 4) ^ (s & 7)) << 2);

  // Fc register prefetch (2 steps ahead): parity(j) buffer holds F(j) (exp'd).
  float4v rA0, rA1, rB0, rB1;

  __builtin_amdgcn_s_barrier();  // B0: chunk 0 ready
  __builtin_amdgcn_sched_barrier(0);
  rA0 = *(const float4v*)(FFd + 0 * SSTRIDE + off0);
  rA1 = *(const float4v*)(FFd + 0 * SSTRIDE + off1);
  rB0 = *(const float4v*)(FFd + 1 * SSTRIDE + off0);
  rB1 = *(const float4v*)(FFd + 1 * SSTRIDE + off1);

#define RENORM_A()                                                            \
  { float mx = fmaxf(fmaxf(fmaxf(a[0], a[1]), fmaxf(a[2], a[3])),             \
                     fmaxf(fmaxf(a[4], a[5]), fmaxf(a[6], a[7])));            \
    mx = fmaxf(mx, __shfl_xor(mx, 16, 64));                                   \
    mx = fmaxf(mx, __shfl_xor(mx, 32, 64));                                   \
    const int ex = (int)((__float_as_uint(mx) >> 23) & 0xFFu) - 127;          \
    const float scl = __uint_as_float((unsigned)(127 - ex) << 23);            \
    _Pragma("unroll") for (int i = 0; i < 8; ++i) a[i] *= scl;                \
    c2 += (float)ex; }

  for (int k = 0; k < NCH; ++k) {
    const float* fb = FFd + (k & 1) * FSLOT;
    const float* mb = MMd + (k & 1) * MSLOT;
    const unsigned fl = __builtin_amdgcn_readfirstlane(FLGd[k & 1]);
    if (fl) {  // -------- fast path: all masks set, no selects --------
#pragma unroll
      for (int j = 0; j < CH; ++j) {
        const float4v F0 = (j & 1) ? rB0 : rA0;
        const float4v F1 = (j & 1) ? rB1 : rA1;
        if (FWD) {
          const float4v D0 = __builtin_amdgcn_mfma_f32_16x16x32_bf16(e0.v, Bf.v, zerov, 0, 0, 0);
          const float4v D1 = __builtin_amdgcn_mfma_f32_16x16x32_bf16(e1.v, Bf.v, zerov, 0, 0, 0);
#pragma unroll
          for (int i = 0; i < 4; ++i) { a[i] = D0[i] * F0[i]; a[4 + i] = D1[i] * F1[i]; }
          if (j == CH - 1) RENORM_A()
          Bf.u[0] = pk_tr(a[0], a[1]); Bf.u[1] = pk_tr(a[2], a[3]);
          Bf.u[2] = pk_tr(a[4], a[5]); Bf.u[3] = pk_tr(a[6], a[7]);
        } else {
          float tb[8];
#pragma unroll
          for (int i = 0; i < 4; ++i) { tb[i] = a[i] * F0[i]; tb[4 + i] = a[4 + i] * F1[i]; }
          Frag8 Bp;
          Bp.u[0] = pk_tr(tb[0], tb[1]); Bp.u[1] = pk_tr(tb[2], tb[3]);
          Bp.u[2] = pk_tr(tb[4], tb[5]); Bp.u[3] = pk_tr(tb[6], tb[7]);
          const float4v D0 = __builtin_amdgcn_mfma_f32_16x16x32_bf16(e0.v, Bp.v, zerov, 0, 0, 0);
          const float4v D1 = __builtin_amdgcn_mfma_f32_16x16x32_bf16(e1.v, Bp.v, zerov, 0, 0, 0);
#pragma unroll
          for (int i = 0; i < 4; ++i) { a[i] = D0[i]; a[4 + i] = D1[i]; }
          if (j == CH - 1) RENORM_A()
        }
        if (j < CH - 2) {  // prefetch F(j+2) into parity-j buffer (WAR safe)
          ((j & 1) ? rB0 : rA0) = *(const float4v*)(fb + (j + 2) * SSTRIDE + off0);
          ((j & 1) ? rB1 : rA1) = *(const float4v*)(fb + (j + 2) * SSTRIDE + off1);
        }
      }
    } else {  // -------- masked path (rare): per-column selects --------
#pragma unroll
      for (int j = 0; j < CH; ++j) {
        const float4v F0 = (j & 1) ? rB0 : rA0;
        const float4v F1 = (j & 1) ? rB1 : rA1;
        const bool mv = (mb[j * BPB + (s & 7)] != 0.0f);
        if (FWD) {
          const float4v D0 = __builtin_amdgcn_mfma_f32_16x16x32_bf16(e0.v, Bf.v, zerov, 0, 0, 0);
          const float4v D1 = __builtin_amdgcn_mfma_f32_16x16x32_bf16(e1.v, Bf.v, zerov, 0, 0, 0);
#pragma unroll
          for (int i = 0; i < 4; ++i) {
            a[i] = mv ? D0[i] * F0[i] : a[i];
            a[4 + i] = mv ? D1[i] * F1[i] : a[4 + i];
          }
          if (j == CH - 1) RENORM_A()
          Bf.u[0] = pk_tr(a[0], a[1]); Bf.u[1] = pk_tr(a[2], a[3]);
          Bf.u[2] = pk_tr(a[4], a[5]); Bf.u[3] = pk_tr(a[6], a[7]);
        } else {
          float tb[8];
#pragma unroll
          for (int i = 0; i < 4; ++i) { tb[i] = a[i] * F0[i]; tb[4 + i] = a[4 + i] * F1[i]; }
          Frag8 Bp;
          Bp.u[0] = pk_tr(tb[0], tb[1]); Bp.u[1] = pk_tr(tb[2], tb[3]);
          Bp.u[2] = pk_tr(tb[4], tb[5]); Bp.u[3] = pk_tr(tb[6], tb[7]);
          const float4v D0 = __builtin_amdgcn_mfma_f32_16x16x32_bf16(e0.v, Bp.v, zerov, 0, 0, 0);
          const float4v D1 = __builtin_amdgcn_mfma_f32_16x16x32_bf16(e1.v, Bp.v, zerov, 0, 0, 0);
#pragma unroll
          for (int i = 0; i < 4; ++i) {
            a[i] = mv ? D0[i] : a[i];
            a[4 + i] = mv ? D1[i] : a[4 + i];
          }
          if (j == CH - 1) RENORM_A()
        }
        if (j < CH - 2) {
          ((j & 1) ? rB0 : rA0) = *(const float4v*)(fb + (j + 2) * SSTRIDE + off0);
          ((j & 1) ? rB1 : rA1) = *(const float4v*)(fb + (j + 2) * SSTRIDE + off1);
        }
      }
    }
    // reads of FF[k&1] retired before producer rewrites it next window
    asm volatile("s_waitcnt lgkmcnt(0)" ::: "memory");
    __builtin_amdgcn_s_barrier();  // B(k+1): FF chunk k+1 ready
    __builtin_amdgcn_sched_barrier(0);
    if (k < NCH - 1) {  // boundary prologue: F(0),F(1) of chunk k+1
      const float* fn = FFd + ((k + 1) & 1) * FSLOT;
      rA0 = *(const float4v*)(fn + 0 * SSTRIDE + off0);
      rA1 = *(const float4v*)(fn + 0 * SSTRIDE + off1);
      rB0 = *(const float4v*)(fn + 1 * SSTRIDE + off0);
      rB1 = *(const float4v*)(fn + 1 * SSTRIDE + off1);
    }
  }
#undef RENORM_A

  // ---- junction: out[b] = ln2 * (c2f + c2b + log2(dot(u, alpha)))
  if (!FWD) {
    float4v lo = {a[0], a[1], a[2], a[3]}, hi = {a[4], a[5], a[6], a[7]};
    *(float4v*)(vbuf + lane * 8) = lo;
    *(float4v*)(vbuf + lane * 8 + 4) = hi;
    if (lane < 8) c2buf[lane] = c2;
  }
  __syncthreads();  // junction barrier
  if (FWD) {
    const float4v v0 = *(const float4v*)(vbuf + lane * 8);
    const float4v v1 = *(const float4v*)(vbuf + lane * 8 + 4);
    float dot = a[0] * v0[0] + a[1] * v0[1] + a[2] * v0[2] + a[3] * v0[3] +
                a[4] * v1[0] + a[5] * v1[1] + a[6] * v1[2] + a[7] * v1[3];
    dot += __shfl_xor(dot, 16, 64);
    dot += __shfl_xor(dot, 32, 64);
    if (lane < 8)
      out[b0 + lane] = LN2 * (c2 + c2buf[lane] + __builtin_amdgcn_logf(dot));
  }
}

extern "C" __global__ void __launch_bounds__(256, 1) crf_scan(
    const float* __restrict__ feats, const float* __restrict__ mask,
    const float* __restrict__ trans, float* __restrict__ out) {
  // Order matters: consumer garbage-column over-reads run up to 255 dwords
  // past the last FF slot of each direction; FF dirs are contiguous and MM
  // follows FF, so all over-reads stay in-bounds don't-care.
  __shared__ float FF[2][2][FSLOT];       // 32 KB exp'd F (parity buffers)
  __shared__ float MM[2][2][MSLOT];       // 2 KB
  __shared__ unsigned FLG[2][2];
  __shared__ float RAW[2][RRN][RSLOT];    // 66 KB raw gld_lds ring
  __shared__ float vbuf[512];             // 2 KB
  __shared__ float c2buf[16];
  const int wid = threadIdx.x >> 6;
  const int lane = threadIdx.x & 63;
  const int b0 = blockIdx.x * BPB;  // 8 batches per block

  if (wid == 0)
    consume<true>(trans, out, &FF[0][0][0], &MM[0][0][0], &FLG[0][0], vbuf, c2buf, b0, lane);
  else if (wid == 1)
    consume<false>(trans, out, &FF[1][0][0], &MM[1][0][0], &FLG[1][0], vbuf, c2buf, b0, lane);
  else if (wid == 2)
    produce<true>(feats, mask, &RAW[0][0][0], &FF[0][0][0], &MM[0][0][0], &FLG[0][0], b0, lane);
  else
    produce<false>(feats, mask, &RAW[1][0][0], &FF[1][0][0], &MM[1][0][0], &FLG[1][0], b0, lane);
}

extern "C" void kernel_launch(void* const* d_in, const int* in_sizes, int n_in,
                              void* d_out, int out_size, void* d_ws, size_t ws_size,
                              hipStream_t stream) {
  const float* feats = (const float*)d_in[0];
  const float* mask  = (const float*)d_in[1];
  const float* trans = (const float*)d_in[2];
  float* out = (float*)d_out;
  hipLaunchKernelGGL(crf_scan, dim3(BATCH / BPB), dim3(256), 0, stream,
                     feats, mask, trans, out);
}